// Round 4
// baseline (182.732 us; speedup 1.0000x reference)
//
#include <hip/hip_runtime.h>
#include <hip/hip_fp16.h>

// B=32768, D=128, L=3, R=64, O=64. fp32 in/out, f16 MFMA compute.
// Cores are L2-resident (2MB, read by all WGs) -> NO LDS staging: each wave
// loads its own B-fragments directly global->VGPR (coalesced 1KB/wave via the
// ct2 prep layout). Main loop is barrier-free, depth-2 reg double-buffered.
// x read exactly once (xn slices 1,2 resident in LDS). Cross-wave reduce via
// 16KB LDS scratch (aliases dead xn0) + LDS atomicAdd.
typedef _Float16 f16x8 __attribute__((ext_vector_type(8)));
typedef float f32x16 __attribute__((ext_vector_type(16)));

union H2x4 { f16x8 v; __half2 h2[4]; unsigned u[4]; };
union U1H2 { unsigned u; __half2 h; };

#define TB 64               // batch rows per workgroup (512 WGs = 2/CU)
// LDS layout (bytes)
#define XN0_OFF 0           // xn0 [row<64][256B swz] = 16KB; aliased as reduce scratch
#define T_OFF    16384      // T buffer [64][64]f16, 128B rows, XOR swz = 8192B
#define XN12_OFF 24576      // xn slices 1,2: [d<128][row<64] 2xf16, pitch 264B = 33792B
#define SMEM_BYTES 58368    // 2 WGs/CU
// workspace layout (bytes)
#define WS_CT1   0          // core1 -> ct2 layout [d][sb][kh][kbL][lane][16B], 1MB
#define WS_CT2   1048576    // core2 same
#define WS_L0T   2097152    // layer0^T [r][d] f16, 16KB
#define WS_LASTT 2113536    // last^T [o][r] f16, 8KB

__device__ __forceinline__ unsigned pack_h2(float a, float b) {
  return (unsigned)__half_as_ushort(__float2half(a)) |
         ((unsigned)__half_as_ushort(__float2half(b)) << 16);
}

// 4-way (p x kh) cross-wave reduce through 16KB LDS scratch (aliases xn0),
// writes T [64][64] f16 swizzled. Accumulators passed BY VALUE (regs).
__device__ __forceinline__ void reduce_T(unsigned char* smem, f32x16 a0, f32x16 a1,
                                         int p, int kh, int h, int scol) {
  float* scr = (float*)(smem + XN0_OFF);  // [64][64] f32 = 16KB
  __syncthreads();
  if ((p | kh) == 0) {                    // group (0,0) plain-writes
#pragma unroll
    for (int j = 0; j < 16; ++j) {
      const int r0 = (j & 3) + 8 * (j >> 2) + 4 * h;
      scr[r0 * 64 + scol] = a0[j];
      scr[(32 + r0) * 64 + scol] = a1[j];
    }
  }
  __syncthreads();
  if ((p | kh) != 0) {                    // other 3 groups atomic-add
#pragma unroll
    for (int j = 0; j < 16; ++j) {
      const int r0 = (j & 3) + 8 * (j >> 2) + 4 * h;
      atomicAdd(&scr[r0 * 64 + scol], a0[j]);
      atomicAdd(&scr[(32 + r0) * 64 + scol], a1[j]);
    }
  }
  __syncthreads();
  if (p == 0) {  // 4 waves (kh,sb,h) cover all 64 rows
#pragma unroll
    for (int j = 0; j < 16; ++j) {
      const int r0 = (j & 3) + 8 * (j >> 2) + 4 * h;
      const int row = kh * 32 + r0;
      *(__half*)(smem + T_OFF + row * 128 + ((2 * scol) ^ ((row & 7) << 4))) =
          __float2half(scr[row * 64 + scol]);
    }
  }
  __syncthreads();
}

// ---- prep: cast weights to f16 in the layouts the main kernel wants ----
__global__ void __launch_bounds__(512) tt_prep(
    const float* __restrict__ layer0, const float* __restrict__ core1,
    const float* __restrict__ core2, const float* __restrict__ last,
    unsigned char* __restrict__ ws) {
  const int tid = blockIdx.x * 512 + threadIdx.x;
  if (tid < 524288) {                       // ct2: 2 x 262144 words
    const int which = tid >> 18;
    const int w = tid & 262143;
    const float* core = which ? core2 : core1;
    unsigned char* ct = ws + (which ? WS_CT2 : WS_CT1);
    // dest layout: [d][sb][kh][kbL][lp=l31*2+h][16B]; offset == w*4 (linear)
    const int j   = w & 3;                  // word within 16B chunk
    const int lp  = (w >> 2) & 63;          // l31*2 + h
    const int blk = w >> 8;                 // d*8 + sb*4 + kh*2 + kbL
    const int kbL = blk & 1;
    const int kh  = (blk >> 1) & 1;
    const int sb  = (blk >> 2) & 1;
    const int d   = blk >> 3;
    const int hh  = lp & 1;
    const int l31 = lp >> 1;
    const int s   = sb * 32 + l31;
    const int r0  = kh * 32 + kbL * 16 + hh * 8 + 2 * j;
    const unsigned val = pack_h2(core[r0 * 8192 + d * 64 + s],
                                 core[(r0 + 1) * 8192 + d * 64 + s]);
    *(unsigned*)(ct + (size_t)w * 4) = val;
  } else if (tid < 528384) {                // l0t: 4096 words, [r][d] f16 (256B rows)
    const int w = tid - 524288;
    const int r = w >> 6, j = w & 63, d = 2 * j;
    const unsigned val = pack_h2(layer0[d * 64 + r], layer0[(d + 1) * 64 + r]);
    *(unsigned*)(ws + WS_L0T + r * 256 + 4 * j) = val;
  } else if (tid < 530432) {                // lastT: 2048 words, [o][r] f16 (128B rows)
    const int w = tid - 528384;
    const int o = w >> 5, j = w & 31, r = 2 * j;
    const unsigned val = pack_h2(last[r * 64 + o], last[(r + 1) * 64 + o]);
    *(unsigned*)(ws + WS_LASTT + o * 128 + 4 * j) = val;
  }
}

// KR-product + 2x2 MFMA block for one d. bf0/bf1 cover r-blocks kbL=0/1.
#define KRMM(BF0, BF1, XV0, XV1)                                              \
  do {                                                                        \
    U1H2 e0, e1;                                                              \
    e0.u = (XV0) | ((XV0) << 16);                                             \
    e1.u = (XV1) | ((XV1) << 16);                                             \
    H2x4 af0, af1;                                                            \
    _Pragma("unroll") for (int q = 0; q < 4; ++q) {                           \
      af0.h2[q] = __hmul2(tp00.h2[q], e0.h);                                  \
      af1.h2[q] = __hmul2(tp10.h2[q], e1.h);                                  \
    }                                                                         \
    acc0 = __builtin_amdgcn_mfma_f32_32x32x16_f16(af0.v, (BF0), acc0, 0, 0, 0); \
    acc1 = __builtin_amdgcn_mfma_f32_32x32x16_f16(af1.v, (BF0), acc1, 0, 0, 0); \
    _Pragma("unroll") for (int q = 0; q < 4; ++q) {                           \
      af0.h2[q] = __hmul2(tp01.h2[q], e0.h);                                  \
      af1.h2[q] = __hmul2(tp11.h2[q], e1.h);                                  \
    }                                                                         \
    acc0 = __builtin_amdgcn_mfma_f32_32x32x16_f16(af0.v, (BF1), acc0, 0, 0, 0); \
    acc1 = __builtin_amdgcn_mfma_f32_32x32x16_f16(af1.v, (BF1), acc1, 0, 0, 0); \
  } while (0)

// ---- fused main kernel: LN + 4-stage tensor-train chain ----
__global__ void __launch_bounds__(512, 4) tt_fused(
    const float* __restrict__ x, const float* __restrict__ lnw,
    const float* __restrict__ lnb, const unsigned char* __restrict__ ws,
    float* __restrict__ out) {
  __shared__ alignas(16) unsigned char smem[SMEM_BYTES];
  const int tid = threadIdx.x;
  const int wid = tid >> 6;
  const int lane = tid & 63;
  const int l31 = lane & 31;
  const int h = lane >> 5;
  const int p  = wid & 1;           // d-parity
  const int kh = (wid >> 1) & 1;    // r-half (K-split over r)
  const int sb = (wid >> 2) & 1;    // s-block (32 cols)
  const int bg0 = blockIdx.x * TB;
  const int scol = sb * 32 + l31;   // this lane's B-col
  const int swzA = (l31 & 7) << 4;  // == (row&7)<<4 for row = mb*32+l31

  // ---------- phase 0: LN; xn0 -> XN0 [row][256B swz]; xn1,2 -> XN12 ----------
  {
    float wv[6], bv[6];
#pragma unroll
    for (int k = 0; k < 6; ++k) { wv[k] = lnw[lane + 64 * k]; bv[k] = lnb[lane + 64 * k]; }
#pragma unroll
    for (int rr = 0; rr < 8; ++rr) {
      const int row = wid * 8 + rr;
      const float* xrow = x + (size_t)(bg0 + row) * 384;
      float v[6];
#pragma unroll
      for (int k = 0; k < 6; ++k) v[k] = xrow[lane + 64 * k];
      float s = 0.f, ss = 0.f;
#pragma unroll
      for (int k = 0; k < 6; ++k) { s += v[k]; ss += v[k] * v[k]; }
#pragma unroll
      for (int m = 1; m < 64; m <<= 1) { s += __shfl_xor(s, m); ss += __shfl_xor(ss, m); }
      const float mu = s * (1.f / 384.f);
      const float var = ss * (1.f / 384.f) - mu * mu;
      const float rstd = rsqrtf(var + 1e-5f);
#pragma unroll
      for (int k = 0; k < 6; ++k) {
        const int i = lane + 64 * k;        // i = 3*d + sl
        const int d = i / 3;
        const int sl = i - 3 * d;
        const float xv = (v[k] - mu) * rstd * wv[k] + bv[k];
        if (sl == 0) {
          *(__half*)(smem + XN0_OFF + row * 256 + ((2 * d) ^ ((row & 7) << 4))) =
              __float2half(xv);
        } else {
          *(__half*)(smem + XN12_OFF + d * 264 + 4 * row + 2 * (sl - 1)) =
              __float2half(xv);
        }
      }
    }
  }
  __syncthreads();

  f32x16 acc0, acc1;  // rows 0..31 / 32..63 of this wave's (kh,sb) partial

  // ---------- stage A: T1 = xn0 @ layer0 (K=128, 4-way (p,kh) K-split) ----------
#pragma unroll
  for (int i = 0; i < 16; ++i) { acc0[i] = 0.f; acc1[i] = 0.f; }
  {
    const unsigned char* l0t = ws + WS_L0T;
#pragma unroll
    for (int kbL = 0; kbL < 2; ++kbL) {
      const int cb = (((p << 1) | kh) * 2 + kbL) * 32 + h * 16;
      f16x8 bf = *(const f16x8*)(l0t + scol * 256 + cb);
      f16x8 a0 = *(const f16x8*)(smem + XN0_OFF + l31 * 256 + (cb ^ swzA));
      f16x8 a1 = *(const f16x8*)(smem + XN0_OFF + (32 + l31) * 256 + (cb ^ swzA));
      acc0 = __builtin_amdgcn_mfma_f32_32x32x16_f16(a0, bf, acc0, 0, 0, 0);
      acc1 = __builtin_amdgcn_mfma_f32_32x32x16_f16(a1, bf, acc1, 0, 0, 0);
    }
  }
  reduce_T(smem, acc0, acc1, p, kh, h, scol);  // -> T1 (scr aliases xn0: dead now)

  // ---------- stages B,C: T = KR(T, xn_l) @ core_l (barrier-free main loop) ----------
  for (int st = 0; st < 2; ++st) {
    // wave's coalesced fragment base: ct2[d][sb][kh][kbL][lp][16B], d = 2*i+p
    const unsigned char* base = ws + (st ? WS_CT2 : WS_CT1) +
                                sb * 4096 + kh * 2048 + (l31 * 2 + h) * 16 +
                                p * 8192;
    const unsigned char* xbase = smem + XN12_OFF + p * 264 + 2 * st + 4 * l31;

    // T rows (both m-blocks x this wave's r-half K=32) into NAMED packed regs
    H2x4 tp00, tp01, tp10, tp11;   // tp<mb><kbL>
    {
      const int rb0 = kh * 64 + h * 16;
      tp00.v = *(const f16x8*)(smem + T_OFF + l31 * 128 + (rb0 ^ swzA));
      tp01.v = *(const f16x8*)(smem + T_OFF + l31 * 128 + ((rb0 + 32) ^ swzA));
      tp10.v = *(const f16x8*)(smem + T_OFF + (32 + l31) * 128 + (rb0 ^ swzA));
      tp11.v = *(const f16x8*)(smem + T_OFF + (32 + l31) * 128 + ((rb0 + 32) ^ swzA));
    }

#pragma unroll
    for (int i = 0; i < 16; ++i) { acc0[i] = 0.f; acc1[i] = 0.f; }

    // depth-2 pipelined stream over i=0..63 (d = 2*i+p): named A/B reg sets
    f16x8 aB0 = *(const f16x8*)(base);
    f16x8 aB1 = *(const f16x8*)(base + 1024);
    unsigned aX0 = *(const unsigned short*)(xbase);
    unsigned aX1 = *(const unsigned short*)(xbase + 128);
#pragma unroll 1
    for (int ii = 0; ii < 32; ++ii) {
      const int i1 = 2 * ii + 1;
      f16x8 bB0 = *(const f16x8*)(base + i1 * 16384);
      f16x8 bB1 = *(const f16x8*)(base + i1 * 16384 + 1024);
      unsigned bX0 = *(const unsigned short*)(xbase + i1 * 528);
      unsigned bX1 = *(const unsigned short*)(xbase + i1 * 528 + 128);
      KRMM(aB0, aB1, aX0, aX1);
      if (ii < 31) {
        const int i2 = 2 * ii + 2;
        aB0 = *(const f16x8*)(base + i2 * 16384);
        aB1 = *(const f16x8*)(base + i2 * 16384 + 1024);
        aX0 = *(const unsigned short*)(xbase + i2 * 528);
        aX1 = *(const unsigned short*)(xbase + i2 * 528 + 128);
      }
      KRMM(bB0, bB1, bX0, bX1);
    }
    reduce_T(smem, acc0, acc1, p, kh, h, scol);  // -> T2 then T3
  }

  // ---------- stage D: out = T3 @ last (p==0 waves; rows kh*32..) ----------
  if (p == 0) {
    f32x16 accd;
#pragma unroll
    for (int i = 0; i < 16; ++i) accd[i] = 0.f;
    const unsigned char* lastT = ws + WS_LASTT;
#pragma unroll
    for (int kb = 0; kb < 4; ++kb) {
      const int cb = kb * 32 + h * 16;
      f16x8 bf = *(const f16x8*)(lastT + scol * 128 + cb);
      f16x8 af = *(const f16x8*)(smem + T_OFF + (kh * 32 + l31) * 128 + (cb ^ swzA));
      accd = __builtin_amdgcn_mfma_f32_32x32x16_f16(af, bf, accd, 0, 0, 0);
    }
#pragma unroll
    for (int j = 0; j < 16; ++j) {
      const int r0 = (j & 3) + 8 * (j >> 2) + 4 * h;
      out[(size_t)(bg0 + kh * 32 + r0) * 64 + scol] = accd[j];
    }
  }
}

extern "C" void kernel_launch(void* const* d_in, const int* in_sizes, int n_in,
                              void* d_out, int out_size, void* d_ws, size_t ws_size,
                              hipStream_t stream) {
  const float* x      = (const float*)d_in[0];
  const float* layer0 = (const float*)d_in[1];
  const float* core1  = (const float*)d_in[2];
  const float* core2  = (const float*)d_in[3];
  const float* last   = (const float*)d_in[4];
  const float* lnw    = (const float*)d_in[5];
  const float* lnb    = (const float*)d_in[6];
  unsigned char* ws   = (unsigned char*)d_ws;
  float* outp         = (float*)d_out;

  tt_prep<<<1036, 512, 0, stream>>>(layer0, core1, core2, last, ws);
  tt_fused<<<512, 512, 0, stream>>>(x, lnw, lnb, ws, outp);
}

// Round 5
// 180.115 us; speedup vs baseline: 1.0145x; 1.0145x over previous
//
#include <hip/hip_runtime.h>
#include <hip/hip_fp16.h>

// B=32768, D=128, L=3, R=64, O=64. fp32 in/out, f16 MFMA compute.
// Cores are L2-resident (2MB, read by all WGs) -> NO LDS staging: each wave
// loads its own B-fragments directly global->VGPR (coalesced 1KB/wave via the
// ct2 prep layout). Main loop is barrier-free, MODULO-SCHEDULED DEPTH-4 with
// four named register sets (strict FIFO issue/consume order -> counted vmcnt).
// x read exactly once (xn slices 1,2 resident in LDS). Cross-wave reduce via
// 16KB LDS scratch (aliases dead xn0) + LDS atomicAdd.
typedef _Float16 f16x8 __attribute__((ext_vector_type(8)));
typedef float f32x16 __attribute__((ext_vector_type(16)));

union H2x4 { f16x8 v; __half2 h2[4]; unsigned u[4]; };
union U1H2 { unsigned u; __half2 h; };

#define TB 64               // batch rows per workgroup (512 WGs = 2/CU)
// LDS layout (bytes)
#define XN0_OFF 0           // xn0 [row<64][256B swz] = 16KB; aliased as reduce scratch
#define T_OFF    16384      // T buffer [64][64]f16, 128B rows, XOR swz = 8192B
#define XN12_OFF 24576      // xn slices 1,2: [d<128][row<64] 2xf16, pitch 264B = 33792B
#define SMEM_BYTES 58368    // 2 WGs/CU
// workspace layout (bytes)
#define WS_CT1   0          // core1 -> ct2 layout [d][sb][kh][kbL][lane][16B], 1MB
#define WS_CT2   1048576    // core2 same
#define WS_L0T   2097152    // layer0^T [r][d] f16, 16KB
#define WS_LASTT 2113536    // last^T [o][r] f16, 8KB

__device__ __forceinline__ unsigned pack_h2(float a, float b) {
  return (unsigned)__half_as_ushort(__float2half(a)) |
         ((unsigned)__half_as_ushort(__float2half(b)) << 16);
}

// 4-way (p x kh) cross-wave reduce through 16KB LDS scratch (aliases xn0),
// writes T [64][64] f16 swizzled. Accumulators passed BY VALUE (regs).
__device__ __forceinline__ void reduce_T(unsigned char* smem, f32x16 a0, f32x16 a1,
                                         int p, int kh, int h, int scol) {
  float* scr = (float*)(smem + XN0_OFF);  // [64][64] f32 = 16KB
  __syncthreads();
  if ((p | kh) == 0) {                    // group (0,0) plain-writes
#pragma unroll
    for (int j = 0; j < 16; ++j) {
      const int r0 = (j & 3) + 8 * (j >> 2) + 4 * h;
      scr[r0 * 64 + scol] = a0[j];
      scr[(32 + r0) * 64 + scol] = a1[j];
    }
  }
  __syncthreads();
  if ((p | kh) != 0) {                    // other 3 groups atomic-add
#pragma unroll
    for (int j = 0; j < 16; ++j) {
      const int r0 = (j & 3) + 8 * (j >> 2) + 4 * h;
      atomicAdd(&scr[r0 * 64 + scol], a0[j]);
      atomicAdd(&scr[(32 + r0) * 64 + scol], a1[j]);
    }
  }
  __syncthreads();
  if (p == 0) {  // 4 waves (kh,sb,h) cover all 64 rows
#pragma unroll
    for (int j = 0; j < 16; ++j) {
      const int r0 = (j & 3) + 8 * (j >> 2) + 4 * h;
      const int row = kh * 32 + r0;
      *(__half*)(smem + T_OFF + row * 128 + ((2 * scol) ^ ((row & 7) << 4))) =
          __float2half(scr[row * 64 + scol]);
    }
  }
  __syncthreads();
}

// ---- prep: cast weights to f16 in the layouts the main kernel wants ----
__global__ void __launch_bounds__(512) tt_prep(
    const float* __restrict__ layer0, const float* __restrict__ core1,
    const float* __restrict__ core2, const float* __restrict__ last,
    unsigned char* __restrict__ ws) {
  const int tid = blockIdx.x * 512 + threadIdx.x;
  if (tid < 524288) {                       // ct2: 2 x 262144 words
    const int which = tid >> 18;
    const int w = tid & 262143;
    const float* core = which ? core2 : core1;
    unsigned char* ct = ws + (which ? WS_CT2 : WS_CT1);
    // dest layout: [d][sb][kh][kbL][lp=l31*2+h][16B]; offset == w*4 (linear)
    const int j   = w & 3;                  // word within 16B chunk
    const int lp  = (w >> 2) & 63;          // l31*2 + h
    const int blk = w >> 8;                 // d*8 + sb*4 + kh*2 + kbL
    const int kbL = blk & 1;
    const int kh  = (blk >> 1) & 1;
    const int sb  = (blk >> 2) & 1;
    const int d   = blk >> 3;
    const int hh  = lp & 1;
    const int l31 = lp >> 1;
    const int s   = sb * 32 + l31;
    const int r0  = kh * 32 + kbL * 16 + hh * 8 + 2 * j;
    const unsigned val = pack_h2(core[r0 * 8192 + d * 64 + s],
                                 core[(r0 + 1) * 8192 + d * 64 + s]);
    *(unsigned*)(ct + (size_t)w * 4) = val;
  } else if (tid < 528384) {                // l0t: 4096 words, [r][d] f16 (256B rows)
    const int w = tid - 524288;
    const int r = w >> 6, j = w & 63, d = 2 * j;
    const unsigned val = pack_h2(layer0[d * 64 + r], layer0[(d + 1) * 64 + r]);
    *(unsigned*)(ws + WS_L0T + r * 256 + 4 * j) = val;
  } else if (tid < 530432) {                // lastT: 2048 words, [o][r] f16 (128B rows)
    const int w = tid - 528384;
    const int o = w >> 5, j = w & 31, r = 2 * j;
    const unsigned val = pack_h2(last[r * 64 + o], last[(r + 1) * 64 + o]);
    *(unsigned*)(ws + WS_LASTT + o * 128 + 4 * j) = val;
  }
}

// KR-product + 2x2 MFMA block for one d. BF0/BF1 cover r-blocks kbL=0/1.
#define KRMM(BF0, BF1, XV0, XV1)                                              \
  do {                                                                        \
    U1H2 e0, e1;                                                              \
    e0.u = (XV0) | ((XV0) << 16);                                             \
    e1.u = (XV1) | ((XV1) << 16);                                             \
    H2x4 af0, af1;                                                            \
    _Pragma("unroll") for (int q = 0; q < 4; ++q) {                           \
      af0.h2[q] = __hmul2(tp00.h2[q], e0.h);                                  \
      af1.h2[q] = __hmul2(tp10.h2[q], e1.h);                                  \
    }                                                                         \
    acc0 = __builtin_amdgcn_mfma_f32_32x32x16_f16(af0.v, (BF0), acc0, 0, 0, 0); \
    acc1 = __builtin_amdgcn_mfma_f32_32x32x16_f16(af1.v, (BF0), acc1, 0, 0, 0); \
    _Pragma("unroll") for (int q = 0; q < 4; ++q) {                           \
      af0.h2[q] = __hmul2(tp01.h2[q], e0.h);                                  \
      af1.h2[q] = __hmul2(tp11.h2[q], e1.h);                                  \
    }                                                                         \
    acc0 = __builtin_amdgcn_mfma_f32_32x32x16_f16(af0.v, (BF1), acc0, 0, 0, 0); \
    acc1 = __builtin_amdgcn_mfma_f32_32x32x16_f16(af1.v, (BF1), acc1, 0, 0, 0); \
  } while (0)

// load one fragment (d = this set's next) into named set S, advance pointers.
// global: 2 x dwordx4/lane (companion at +1024 folds into the imm offset);
// LDS xn: 2 x u16 (companion at +128 imm).
#define LOADSET(S)                                                            \
  do {                                                                        \
    S##B0 = *(const f16x8*)(g##S);                                            \
    S##B1 = *(const f16x8*)(g##S + 1024);                                     \
    S##X0 = *(const unsigned short*)(x##S);                                   \
    S##X1 = *(const unsigned short*)(x##S + 128);                             \
    g##S += 65536;                                                            \
    x##S += 2112;                                                             \
  } while (0)

#define KRMMS(S) KRMM(S##B0, S##B1, S##X0, S##X1)

// ---- fused main kernel: LN + 4-stage tensor-train chain ----
__global__ void __launch_bounds__(512, 4) tt_fused(
    const float* __restrict__ x, const float* __restrict__ lnw,
    const float* __restrict__ lnb, const unsigned char* __restrict__ ws,
    float* __restrict__ out) {
  __shared__ alignas(16) unsigned char smem[SMEM_BYTES];
  const int tid = threadIdx.x;
  const int wid = tid >> 6;
  const int lane = tid & 63;
  const int l31 = lane & 31;
  const int h = lane >> 5;
  const int p  = wid & 1;           // d-parity
  const int kh = (wid >> 1) & 1;    // r-half (K-split over r)
  const int sb = (wid >> 2) & 1;    // s-block (32 cols)
  const int bg0 = blockIdx.x * TB;
  const int scol = sb * 32 + l31;   // this lane's B-col
  const int swzA = (l31 & 7) << 4;  // == (row&7)<<4 for row = mb*32+l31

  // ---------- phase 0: LN; xn0 -> XN0 [row][256B swz]; xn1,2 -> XN12 ----------
  {
    float wv[6], bv[6];
#pragma unroll
    for (int k = 0; k < 6; ++k) { wv[k] = lnw[lane + 64 * k]; bv[k] = lnb[lane + 64 * k]; }
#pragma unroll
    for (int rr = 0; rr < 8; ++rr) {
      const int row = wid * 8 + rr;
      const float* xrow = x + (size_t)(bg0 + row) * 384;
      float v[6];
#pragma unroll
      for (int k = 0; k < 6; ++k) v[k] = xrow[lane + 64 * k];
      float s = 0.f, ss = 0.f;
#pragma unroll
      for (int k = 0; k < 6; ++k) { s += v[k]; ss += v[k] * v[k]; }
#pragma unroll
      for (int m = 1; m < 64; m <<= 1) { s += __shfl_xor(s, m); ss += __shfl_xor(ss, m); }
      const float mu = s * (1.f / 384.f);
      const float var = ss * (1.f / 384.f) - mu * mu;
      const float rstd = rsqrtf(var + 1e-5f);
#pragma unroll
      for (int k = 0; k < 6; ++k) {
        const int i = lane + 64 * k;        // i = 3*d + sl
        const int d = i / 3;
        const int sl = i - 3 * d;
        const float xv = (v[k] - mu) * rstd * wv[k] + bv[k];
        if (sl == 0) {
          *(__half*)(smem + XN0_OFF + row * 256 + ((2 * d) ^ ((row & 7) << 4))) =
              __float2half(xv);
        } else {
          *(__half*)(smem + XN12_OFF + d * 264 + 4 * row + 2 * (sl - 1)) =
              __float2half(xv);
        }
      }
    }
  }
  __syncthreads();

  f32x16 acc0, acc1;  // rows 0..31 / 32..63 of this wave's (kh,sb) partial

  // ---------- stage A: T1 = xn0 @ layer0 (K=128, 4-way (p,kh) K-split) ----------
#pragma unroll
  for (int i = 0; i < 16; ++i) { acc0[i] = 0.f; acc1[i] = 0.f; }
  {
    const unsigned char* l0t = ws + WS_L0T;
#pragma unroll
    for (int kbL = 0; kbL < 2; ++kbL) {
      const int cb = (((p << 1) | kh) * 2 + kbL) * 32 + h * 16;
      f16x8 bf = *(const f16x8*)(l0t + scol * 256 + cb);
      f16x8 a0 = *(const f16x8*)(smem + XN0_OFF + l31 * 256 + (cb ^ swzA));
      f16x8 a1 = *(const f16x8*)(smem + XN0_OFF + (32 + l31) * 256 + (cb ^ swzA));
      acc0 = __builtin_amdgcn_mfma_f32_32x32x16_f16(a0, bf, acc0, 0, 0, 0);
      acc1 = __builtin_amdgcn_mfma_f32_32x32x16_f16(a1, bf, acc1, 0, 0, 0);
    }
  }
  reduce_T(smem, acc0, acc1, p, kh, h, scol);  // -> T1 (scr aliases xn0: dead now)

  // ---------- stages B,C: T = KR(T, xn_l) @ core_l (barrier-free main loop) ----------
  for (int st = 0; st < 2; ++st) {
    // wave's coalesced fragment base: ct2[d][sb][kh][kbL][lp][16B], d = 2*i+p
    const unsigned char* base = ws + (st ? WS_CT2 : WS_CT1) +
                                sb * 4096 + kh * 2048 + (l31 * 2 + h) * 16 +
                                p * 8192;
    const unsigned char* xbase = smem + XN12_OFF + p * 264 + 2 * st + 4 * l31;

    // T rows (both m-blocks x this wave's r-half K=32) into NAMED packed regs
    H2x4 tp00, tp01, tp10, tp11;   // tp<mb><kbL>
    {
      const int rb0 = kh * 64 + h * 16;
      tp00.v = *(const f16x8*)(smem + T_OFF + l31 * 128 + (rb0 ^ swzA));
      tp01.v = *(const f16x8*)(smem + T_OFF + l31 * 128 + ((rb0 + 32) ^ swzA));
      tp10.v = *(const f16x8*)(smem + T_OFF + (32 + l31) * 128 + (rb0 ^ swzA));
      tp11.v = *(const f16x8*)(smem + T_OFF + (32 + l31) * 128 + ((rb0 + 32) ^ swzA));
    }

#pragma unroll
    for (int i = 0; i < 16; ++i) { acc0[i] = 0.f; acc1[i] = 0.f; }

    // ---- modulo-scheduled depth-4 stream over frag i=0..63 (d = 2*i+p) ----
    // Sets A,B,C,D rotate; issue order == consume order (FIFO) so the
    // compiler emits counted vmcnt waits; consume-to-issue distance = 3
    // KRMM blocks (~400 cyc) > L2 latency (~225 cyc).
    f16x8 AB0, AB1, BB0, BB1, CB0, CB1, DB0, DB1;
    unsigned AX0, AX1, BX0, BX1, CX0, CX1, DX0, DX1;
    const unsigned char* gA = base;
    const unsigned char* gB = base + 16384;
    const unsigned char* gC = base + 32768;
    const unsigned char* gD = base + 49152;
    const unsigned char* xA = xbase;
    const unsigned char* xB = xbase + 528;
    const unsigned char* xC = xbase + 1056;
    const unsigned char* xD = xbase + 1584;
    LOADSET(A);  // frag 0
    LOADSET(B);  // frag 1
    LOADSET(C);  // frag 2
    LOADSET(D);  // frag 3
#pragma unroll 1
    for (int ii = 0; ii < 15; ++ii) {   // bodies compute frags 4*ii .. 4*ii+3
      KRMMS(A); LOADSET(A);             // compute 4ii+0, issue 4ii+4
      KRMMS(B); LOADSET(B);             // compute 4ii+1, issue 4ii+5
      KRMMS(C); LOADSET(C);
      KRMMS(D); LOADSET(D);
    }
    KRMMS(A);   // frags 60..63
    KRMMS(B);
    KRMMS(C);
    KRMMS(D);

    reduce_T(smem, acc0, acc1, p, kh, h, scol);  // -> T2 then T3
  }

  // ---------- stage D: out = T3 @ last (p==0 waves; rows kh*32..) ----------
  if (p == 0) {
    f32x16 accd;
#pragma unroll
    for (int i = 0; i < 16; ++i) accd[i] = 0.f;
    const unsigned char* lastT = ws + WS_LASTT;
#pragma unroll
    for (int kb = 0; kb < 4; ++kb) {
      const int cb = kb * 32 + h * 16;
      f16x8 bf = *(const f16x8*)(lastT + scol * 128 + cb);
      f16x8 af = *(const f16x8*)(smem + T_OFF + (kh * 32 + l31) * 128 + (cb ^ swzA));
      accd = __builtin_amdgcn_mfma_f32_32x32x16_f16(af, bf, accd, 0, 0, 0);
    }
#pragma unroll
    for (int j = 0; j < 16; ++j) {
      const int r0 = (j & 3) + 8 * (j >> 2) + 4 * h;
      out[(size_t)(bg0 + kh * 32 + r0) * 64 + scol] = accd[j];
    }
  }
}

extern "C" void kernel_launch(void* const* d_in, const int* in_sizes, int n_in,
                              void* d_out, int out_size, void* d_ws, size_t ws_size,
                              hipStream_t stream) {
  const float* x      = (const float*)d_in[0];
  const float* layer0 = (const float*)d_in[1];
  const float* core1  = (const float*)d_in[2];
  const float* core2  = (const float*)d_in[3];
  const float* last   = (const float*)d_in[4];
  const float* lnw    = (const float*)d_in[5];
  const float* lnb    = (const float*)d_in[6];
  unsigned char* ws   = (unsigned char*)d_ws;
  float* outp         = (float*)d_out;

  tt_prep<<<1036, 512, 0, stream>>>(layer0, core1, core2, last, ws);
  tt_fused<<<512, 512, 0, stream>>>(x, lnw, lnb, ws, outp);
}